// Round 2
// baseline (148.417 us; speedup 1.0000x reference)
//
#include <hip/hip_runtime.h>

#define G_ 8
#define DIN 128
#define ACT 16
#define H1 600
#define H2 500
#define H1P 608
#define H2P 512
#define BT 128
#define NBLK 512
#define NCHUNK 19
#define NTHR 512

// ws offsets (bytes)
#define OFF_W2S 0
#define OFF_W1  622592
#define OFF_W2A 1867776
#define OFF_B1  1998848
#define OFF_B2S 2018304
#define OFF_W3  2020352

// LDS offsets (bytes, dynamic smem)
#define LDS_H1  0u        // 2 x 8 KB : [buf][ft*4+nt][lane]*16B  (layer2 B frags)
#define LDS_W1  16384u    // 2 x 8 KB : [buf][ks*2+ft][lane]*16B  (layer1 A frags)
#define LDS_IDX 32768u    // 128 ints
#define LDS_TOTAL 33280

typedef __attribute__((ext_vector_type(8))) short short8;
typedef __attribute__((ext_vector_type(4))) float f32x4;
typedef __attribute__((ext_vector_type(16))) float f32x16;

__device__ __forceinline__ unsigned short f2bf(float f) {
  unsigned u = __float_as_uint(f);
  unsigned r = u + 0x7fffu + ((u >> 16) & 1u);
  return (unsigned short)(r >> 16);
}

__device__ __forceinline__ short8 pack8(const float* v) {
  short8 p;
#pragma unroll
  for (int j = 0; j < 8; ++j) p[j] = (short)f2bf(v[j]);
  return p;
}

__device__ __forceinline__ void stage1k(unsigned lds_off, const void* g) {
  __builtin_amdgcn_global_load_lds(
      (const __attribute__((address_space(1))) unsigned int*)(unsigned long long)g,
      (__attribute__((address_space(3))) unsigned int*)lds_off,
      16, 0, 0);
}

// ---------------- prep: build frag-linear bf16 images (vectorized) ----------------
__global__ __launch_bounds__(256) void prep_kernel(
    const float* __restrict__ W1, const float* __restrict__ b1,
    const float* __restrict__ W2s, const float* __restrict__ b2s,
    const float* __restrict__ W2a, const float* __restrict__ W3,
    char* __restrict__ ws)
{
  short8* w2s_img = (short8*)(ws + OFF_W2S);
  short8* w1_img  = (short8*)(ws + OFF_W1);
  short8* w2a_img = (short8*)(ws + OFF_W2A);
  float* b1p  = (float*)(ws + OFF_B1);
  float* b2sp = (float*)(ws + OFF_B2S);
  float* w3p  = (float*)(ws + OFF_W3);
  const int tid = blockIdx.x * blockDim.x + threadIdx.x;
  const int nthr = gridDim.x * blockDim.x;

  // W2s image units: [chunk19][t2][ct16][lane64] of 8 bf16
  for (int u = tid; u < 38912; u += nthr) {
    const int e0 = u << 3;
    const int chunk = e0 >> 14, t = (e0 >> 13) & 1, ct = (e0 >> 9) & 15, l = (e0 >> 3) & 63;
    const int cc = ct * 32 + (l & 31);
    const int k0 = chunk * 32 + t * 16 + ((l >> 5) << 3);
    float v[8];
    if (cc < H2 && k0 < H1) {
      const float* p = W2s + (size_t)cc * H1 + k0;
      f32x4 a0 = *(const f32x4*)p, a1 = *(const f32x4*)(p + 4);
      v[0]=a0[0];v[1]=a0[1];v[2]=a0[2];v[3]=a0[3];
      v[4]=a1[0];v[5]=a1[1];v[6]=a1[2];v[7]=a1[3];
    } else {
#pragma unroll
      for (int j = 0; j < 8; ++j) v[j] = 0.f;
    }
    w2s_img[u] = pack8(v);
  }
  // W1 image units: [g8][chunk19][ks4][ft2][lane64] of 8 bf16
  for (int u = tid; u < 77824; u += nthr) {
    const int g = u / 9728;
    const int rem = u - g * 9728;
    const int chunk = rem >> 9;
    const int rem2 = rem & 511;
    const int ks = rem2 >> 7, ft = (rem2 >> 6) & 1, l = rem2 & 63;
    const int f = chunk * 32 + ft * 16 + (l & 15);
    const int d0 = ks * 32 + ((l >> 4) << 3);
    float v[8];
    if (f < H1) {
      const float* p = W1 + ((size_t)g * H1 + f) * DIN + d0;
      f32x4 a0 = *(const f32x4*)p, a1 = *(const f32x4*)(p + 4);
      v[0]=a0[0];v[1]=a0[1];v[2]=a0[2];v[3]=a0[3];
      v[4]=a1[0];v[5]=a1[1];v[6]=a1[2];v[7]=a1[3];
    } else {
#pragma unroll
      for (int j = 0; j < 8; ++j) v[j] = 0.f;
    }
    w1_img[u] = pack8(v);
  }
  // W2a image units: [g8][ct16][lane64] of 8 bf16
  for (int u = tid; u < 8192; u += nthr) {
    const int g = u >> 10, ct = (u >> 6) & 15, l = u & 63;
    const int cc = ct * 32 + (l & 31);
    const int a0 = (l >> 5) << 3;
    float v[8];
    if (cc < H2) {
      const float* p = W2a + ((size_t)g * H2 + cc) * ACT + a0;
      f32x4 x0 = *(const f32x4*)p, x1 = *(const f32x4*)(p + 4);
      v[0]=x0[0];v[1]=x0[1];v[2]=x0[2];v[3]=x0[3];
      v[4]=x1[0];v[5]=x1[1];v[6]=x1[2];v[7]=x1[3];
    } else {
#pragma unroll
      for (int j = 0; j < 8; ++j) v[j] = 0.f;
    }
    w2a_img[u] = pack8(v);
  }
  for (int e = tid; e < G_ * H1P; e += nthr) {
    int g = e / H1P, f = e - g * H1P;
    b1p[e] = (f < H1) ? b1[g * H1 + f] : 0.f;
  }
  for (int e = tid; e < H2P; e += nthr)
    b2sp[e] = (e < H2) ? b2s[e] : 0.f;
  for (int e = tid; e < G_ * H2P; e += nthr) {
    int g = e >> 9, c = e & 511;
    w3p[e] = (c < H2) ? W3[g * H2 + c] : 0.f;
  }
}

// ---------------- main fused kernel ----------------
// 512 blocks: blockIdx = sample-tile*2 + h; block computes H2 cols [h*256, h*256+256)
// 8 waves: wave w -> layer2 (ct pair cp=w&3, nt pair np=w>>2); layer1 sample-tile w.
__global__ __launch_bounds__(NTHR, 4) void critic_main(
    const float* __restrict__ state, const float* __restrict__ action,
    const int* __restrict__ idx, const float* __restrict__ b3,
    const char* __restrict__ ws, float* __restrict__ out)
{
  extern __shared__ char smem[];
  const int tid  = threadIdx.x;
  const int lane = tid & 63;
  const int w    = tid >> 6;
  const int h    = blockIdx.x & 1;
  const int s0   = (blockIdx.x >> 1) * BT;
  const int cp   = w & 3;
  const int np   = w >> 2;
  int* idx_lds = (int*)(smem + LDS_IDX);

  const unsigned short* w2simg = (const unsigned short*)(ws + OFF_W2S);
  const unsigned short* w1img  = (const unsigned short*)(ws + OFF_W1);
  const unsigned short* w2aimg = (const unsigned short*)(ws + OFF_W2A);
  const float* b1p  = (const float*)(ws + OFF_B1);
  const float* b2sp = (const float*)(ws + OFF_B2S);
  const float* w3p  = (const float*)(ws + OFF_W3);

  if (tid < BT) idx_lds[tid] = idx[s0 + tid];

  // ---- state B-frags into registers (16 VGPR) ----
  short8 bs[4];
  {
    const float* sp = state + (size_t)(s0 + w * 16 + (lane & 15)) * DIN + ((lane >> 4) << 3);
#pragma unroll
    for (int ks = 0; ks < 4; ++ks) {
      float v[8];
      f32x4 t0 = *(const f32x4*)(sp + ks * 32);
      f32x4 t1 = *(const f32x4*)(sp + ks * 32 + 4);
      v[0]=t0[0];v[1]=t0[1];v[2]=t0[2];v[3]=t0[3];
      v[4]=t1[0];v[5]=t1[1];v[6]=t1[2];v[7]=t1[3];
      bs[ks] = pack8(v);
    }
  }
  // ---- action B-frags (2 nt tiles) ----
  short8 bact[2];
#pragma unroll
  for (int nti = 0; nti < 2; ++nti) {
    const int nt = 2 * np + nti;
    const float* ap = action + (size_t)(s0 + nt * 32 + (lane & 31)) * ACT + ((lane >> 5) << 3);
    float v[8];
    f32x4 a0 = *(const f32x4*)ap, a1 = *(const f32x4*)(ap + 4);
    v[0]=a0[0];v[1]=a0[1];v[2]=a0[2];v[3]=a0[3];
    v[4]=a1[0];v[5]=a1[1];v[6]=a1[2];v[7]=a1[3];
    bact[nti] = pack8(v);
  }
  __syncthreads();

  const int g_lo = idx_lds[0];
  const int g_hi = idx_lds[BT - 1];

  // stage W1 chunks 0 (buf0) and 1 (buf1): 8 KB each, 1 load/thread
  stage1k(LDS_W1 + (unsigned)(tid * 16),
          ws + OFF_W1 + ((size_t)(g_lo * NCHUNK + 0)) * 8192 + tid * 16);
  stage1k(LDS_W1 + (unsigned)(8192 + tid * 16),
          ws + OFF_W1 + ((size_t)(g_lo * NCHUNK + 1)) * 8192 + tid * 16);

  // ---- acc init: h2a = W2a[g] . action, per-sample masked ----
  f32x16 acc[2][2];
#pragma unroll
  for (int a = 0; a < 2; ++a)
#pragma unroll
    for (int n = 0; n < 2; ++n)
#pragma unroll
      for (int r = 0; r < 16; ++r) acc[a][n][r] = 0.f;
  for (int g = g_lo; g <= g_hi; ++g) {
#pragma unroll
    for (int cti = 0; cti < 2; ++cti) {
      const int ctg = h * 8 + cp * 2 + cti;
      short8 af = *(const short8*)(w2aimg + (((size_t)g * 16 + ctg) * 64 + lane) * 8);
#pragma unroll
      for (int nti = 0; nti < 2; ++nti) {
        f32x16 z;
#pragma unroll
        for (int r = 0; r < 16; ++r) z[r] = 0.f;
        f32x16 t = __builtin_amdgcn_mfma_f32_32x32x16_bf16(af, bact[nti], z, 0, 0, 0);
        const bool p = (idx_lds[(2 * np + nti) * 32 + (lane & 31)] == g);
#pragma unroll
        for (int r = 0; r < 16; ++r) acc[cti][nti][r] = p ? t[r] : acc[cti][nti][r];
      }
    }
  }

  asm volatile("s_waitcnt vmcnt(0)" ::: "memory");
  __syncthreads();

  // layer-1 for chunk c (32 features) -> h1 slab [buf]; per-game masked merge
  auto layer1 = [&](int c, int buf) {
    for (int g = g_lo; g <= g_hi; ++g) {
      f32x4 a1acc[2];
#pragma unroll
      for (int ft = 0; ft < 2; ++ft) { a1acc[ft][0]=0.f;a1acc[ft][1]=0.f;a1acc[ft][2]=0.f;a1acc[ft][3]=0.f; }
#pragma unroll
      for (int ks = 0; ks < 4; ++ks) {
#pragma unroll
        for (int ft = 0; ft < 2; ++ft) {
          short8 aw;
          if (g == g_lo)
            aw = *(const short8*)(smem + LDS_W1 + (unsigned)(buf * 8192 + (ks * 2 + ft) * 1024 + lane * 16));
          else
            aw = *(const short8*)(w1img + (((size_t)g * NCHUNK + c) * 8 + ks * 2 + ft) * 512 + lane * 8);
          a1acc[ft] = __builtin_amdgcn_mfma_f32_16x16x32_bf16(aw, bs[ks], a1acc[ft], 0, 0, 0);
        }
      }
      const int sl = w * 16 + (lane & 15);
      if (idx_lds[sl] == g) {
        const int kloc  = (lane >> 4) << 2;   // 0,4,8,12
        const int khalf = lane >> 5;
        const int j0    = kloc & 7;
        const int nt    = w >> 1;
        const int s32   = (w & 1) * 16 + (lane & 15);
#pragma unroll
        for (int ft = 0; ft < 2; ++ft) {
          const int fglob = c * 32 + ft * 16 + kloc;
          unsigned long long pkv = 0ull;
#pragma unroll
          for (int r = 0; r < 4; ++r) {
            float hv = fmaxf(a1acc[ft][r] + b1p[g * H1P + fglob + r], 0.f);
            pkv |= ((unsigned long long)f2bf(hv)) << (16 * r);
          }
          const unsigned off = LDS_H1 + (unsigned)(buf * 8192 + (ft * 4 + nt) * 1024 + (khalf * 32 + s32) * 16 + j0 * 2);
          *(unsigned long long*)(smem + off) = pkv;
        }
      }
    }
  };

  layer1(0, 0);
  __syncthreads();

  // ---- main loop over 19 chunks: one barrier per chunk ----
  for (int i = 0; i < NCHUNK; ++i) {
    const int cur = i & 1, nxt = cur ^ 1;
    if (i + 2 < NCHUNK)
      stage1k(LDS_W1 + (unsigned)(cur * 8192 + tid * 16),
              ws + OFF_W1 + ((size_t)(g_lo * NCHUNK + i + 2)) * 8192 + tid * 16);

    __builtin_amdgcn_s_setprio(1);
#pragma unroll
    for (int t = 0; t < 2; ++t) {
      short8 bf0 = *(const short8*)(smem + LDS_H1 + (unsigned)(cur * 8192 + (t * 4 + 2 * np) * 1024 + lane * 16));
      short8 bf1 = *(const short8*)(smem + LDS_H1 + (unsigned)(cur * 8192 + (t * 4 + 2 * np + 1) * 1024 + lane * 16));
      const unsigned short* abase = w2simg + (((size_t)((i * 2 + t) * 16 + h * 8 + cp * 2)) * 64 + lane) * 8;
      short8 af0 = *(const short8*)(abase);
      short8 af1 = *(const short8*)(abase + 512);
      acc[0][0] = __builtin_amdgcn_mfma_f32_32x32x16_bf16(af0, bf0, acc[0][0], 0, 0, 0);
      acc[0][1] = __builtin_amdgcn_mfma_f32_32x32x16_bf16(af0, bf1, acc[0][1], 0, 0, 0);
      acc[1][0] = __builtin_amdgcn_mfma_f32_32x32x16_bf16(af1, bf0, acc[1][0], 0, 0, 0);
      acc[1][1] = __builtin_amdgcn_mfma_f32_32x32x16_bf16(af1, bf1, acc[1][1], 0, 0, 0);
    }
    __builtin_amdgcn_s_setprio(0);

    if (i + 1 < NCHUNK) layer1(i + 1, nxt);
    asm volatile("s_waitcnt vmcnt(0)" ::: "memory");
    __syncthreads();
  }

  // ---- epilogue: bias + relu + W3[g] dot + reduce + atomicAdd ----
  float qp[2] = {0.f, 0.f};
  int gs[2];
#pragma unroll
  for (int nti = 0; nti < 2; ++nti) gs[nti] = idx_lds[(2 * np + nti) * 32 + (lane & 31)];
#pragma unroll
  for (int cti = 0; cti < 2; ++cti) {
    const int cbase = h * 256 + (cp * 2 + cti) * 32 + ((lane >> 5) << 2);
#pragma unroll
    for (int r = 0; r < 16; ++r) {
      const int c = cbase + (r & 3) + ((r >> 2) << 3);
      const float b2v = b2sp[c];
#pragma unroll
      for (int nti = 0; nti < 2; ++nti) {
        float v2 = fmaxf(acc[cti][nti][r] + b2v, 0.f);
        qp[nti] += v2 * w3p[gs[nti] * H2P + c];
      }
    }
  }
#pragma unroll
  for (int nti = 0; nti < 2; ++nti) {
    float v = qp[nti];
    v += __shfl_xor(v, 32, 64);
    if (lane < 32) {
      const int sl = (2 * np + nti) * 32 + lane;
      if (h == 0 && cp == 0) v += b3[idx_lds[sl]];
      atomicAdd(out + s0 + sl, v);
    }
  }
}

extern "C" void kernel_launch(void* const* d_in, const int* in_sizes, int n_in,
                              void* d_out, int out_size, void* d_ws, size_t ws_size,
                              hipStream_t stream) {
  const float* state  = (const float*)d_in[0];
  const float* action = (const float*)d_in[1];
  const int*   idx    = (const int*)d_in[2];
  const float* W1     = (const float*)d_in[3];
  const float* b1     = (const float*)d_in[4];
  const float* W2s    = (const float*)d_in[5];
  const float* b2s    = (const float*)d_in[6];
  const float* W2a    = (const float*)d_in[7];
  const float* W3     = (const float*)d_in[8];
  const float* b3     = (const float*)d_in[9];
  float* out = (float*)d_out;
  char* ws = (char*)d_ws;

  hipMemsetAsync(d_out, 0, 32768 * sizeof(float), stream);
  hipLaunchKernelGGL(prep_kernel, dim3(256), dim3(256), 0, stream,
                     W1, b1, W2s, b2s, W2a, W3, ws);
  hipLaunchKernelGGL(critic_main, dim3(NBLK), dim3(NTHR), LDS_TOTAL, stream,
                     state, action, idx, b3, ws, out);
}

// Round 3
// 138.550 us; speedup vs baseline: 1.0712x; 1.0712x over previous
//
#include <hip/hip_runtime.h>

#define G_ 8
#define DIN 128
#define ACT 16
#define H1 600
#define H2 500
#define H1P 608
#define H2P 512
#define BT 128
#define NBLK 256
#define NCHUNK 19
#define NTHR 512

// ws offsets (bytes)
#define OFF_W2S 0
#define OFF_W1  622592
#define OFF_W2A 1867776
#define OFF_B1  1998848
#define OFF_B2S 2018304
#define OFF_W3  2020352
#define OFF_H1  2097152   // 256*19*8192 = 39,845,888 B

// L1 LDS
#define L1_W1SLAB 0u       // 19 * 8192 = 155,648
#define L1_IDX    155648u
#define L1_TOTAL  156160
// L2 LDS
#define L2_W2S 0u          // 2 x 32 KB
#define L2_H1B 65536u      // 2 x 8 KB
#define L2_RED 81920u      // 8*128*4 = 4 KB
#define L2_IDX 86016u
#define L2_TOTAL 86528

typedef __attribute__((ext_vector_type(8))) short short8;
typedef __attribute__((ext_vector_type(4))) float f32x4;
typedef __attribute__((ext_vector_type(16))) float f32x16;

__device__ __forceinline__ unsigned short f2bf(float f) {
  unsigned u = __float_as_uint(f);
  unsigned r = u + 0x7fffu + ((u >> 16) & 1u);
  return (unsigned short)(r >> 16);
}

__device__ __forceinline__ short8 pack8(const float* v) {
  short8 p;
#pragma unroll
  for (int j = 0; j < 8; ++j) p[j] = (short)f2bf(v[j]);
  return p;
}

__device__ __forceinline__ void stage1k(unsigned lds_off, const void* g) {
  __builtin_amdgcn_global_load_lds(
      (const __attribute__((address_space(1))) unsigned int*)(unsigned long long)g,
      (__attribute__((address_space(3))) unsigned int*)lds_off,
      16, 0, 0);
}

// ---------------- prep: build frag-linear bf16 images ----------------
__global__ __launch_bounds__(256) void prep_kernel(
    const float* __restrict__ W1, const float* __restrict__ b1,
    const float* __restrict__ W2s, const float* __restrict__ b2s,
    const float* __restrict__ W2a, const float* __restrict__ W3,
    char* __restrict__ ws)
{
  short8* w2s_img = (short8*)(ws + OFF_W2S);
  short8* w1_img  = (short8*)(ws + OFF_W1);
  short8* w2a_img = (short8*)(ws + OFF_W2A);
  float* b1p  = (float*)(ws + OFF_B1);
  float* b2sp = (float*)(ws + OFF_B2S);
  float* w3p  = (float*)(ws + OFF_W3);
  const int tid = blockIdx.x * blockDim.x + threadIdx.x;
  const int nthr = gridDim.x * blockDim.x;

  // W2s image units: [kstep19][t2][ct16][lane64] of 8 bf16 (k = step*32+t*16+(l>>5)*8+j)
  for (int u = tid; u < 38912; u += nthr) {
    const int e0 = u << 3;
    const int chunk = e0 >> 14, t = (e0 >> 13) & 1, ct = (e0 >> 9) & 15, l = (e0 >> 3) & 63;
    const int cc = ct * 32 + (l & 31);
    const int k0 = chunk * 32 + t * 16 + ((l >> 5) << 3);
    float v[8];
    if (cc < H2 && k0 < H1) {
      const float* p = W2s + (size_t)cc * H1 + k0;
      f32x4 a0 = *(const f32x4*)p, a1 = *(const f32x4*)(p + 4);
      v[0]=a0[0];v[1]=a0[1];v[2]=a0[2];v[3]=a0[3];
      v[4]=a1[0];v[5]=a1[1];v[6]=a1[2];v[7]=a1[3];
    } else {
#pragma unroll
      for (int j = 0; j < 8; ++j) v[j] = 0.f;
    }
    w2s_img[u] = pack8(v);
  }
  // W1 image units: [g8][chunk19][ks4][ft2][lane64] of 8 bf16
  for (int u = tid; u < 77824; u += nthr) {
    const int g = u / 9728;
    const int rem = u - g * 9728;
    const int chunk = rem >> 9;
    const int rem2 = rem & 511;
    const int ks = rem2 >> 7, ft = (rem2 >> 6) & 1, l = rem2 & 63;
    const int f = chunk * 32 + ft * 16 + (l & 15);
    const int d0 = ks * 32 + ((l >> 4) << 3);
    float v[8];
    if (f < H1) {
      const float* p = W1 + ((size_t)g * H1 + f) * DIN + d0;
      f32x4 a0 = *(const f32x4*)p, a1 = *(const f32x4*)(p + 4);
      v[0]=a0[0];v[1]=a0[1];v[2]=a0[2];v[3]=a0[3];
      v[4]=a1[0];v[5]=a1[1];v[6]=a1[2];v[7]=a1[3];
    } else {
#pragma unroll
      for (int j = 0; j < 8; ++j) v[j] = 0.f;
    }
    w1_img[u] = pack8(v);
  }
  // W2a image units: [g8][ct16][lane64] of 8 bf16
  for (int u = tid; u < 8192; u += nthr) {
    const int g = u >> 10, ct = (u >> 6) & 15, l = u & 63;
    const int cc = ct * 32 + (l & 31);
    const int a0 = (l >> 5) << 3;
    float v[8];
    if (cc < H2) {
      const float* p = W2a + ((size_t)g * H2 + cc) * ACT + a0;
      f32x4 x0 = *(const f32x4*)p, x1 = *(const f32x4*)(p + 4);
      v[0]=x0[0];v[1]=x0[1];v[2]=x0[2];v[3]=x0[3];
      v[4]=x1[0];v[5]=x1[1];v[6]=x1[2];v[7]=x1[3];
    } else {
#pragma unroll
      for (int j = 0; j < 8; ++j) v[j] = 0.f;
    }
    w2a_img[u] = pack8(v);
  }
  for (int e = tid; e < G_ * H1P; e += nthr) {
    int g = e / H1P, f = e - g * H1P;
    b1p[e] = (f < H1) ? b1[g * H1 + f] : 0.f;
  }
  for (int e = tid; e < H2P; e += nthr)
    b2sp[e] = (e < H2) ? b2s[e] : 0.f;
  for (int e = tid; e < G_ * H2P; e += nthr) {
    int g = e >> 9, c = e & 511;
    w3p[e] = (c < H2) ? W3[g * H2 + c] : 0.f;
  }
}

// ---------------- L1: state -> h1 image (bf16, frag-linear) ----------------
// 256 blocks x 512 thr. Wave w: samples w*16..w*16+15, all 608 feats.
__global__ __launch_bounds__(NTHR, 2) void l1_kernel(
    const float* __restrict__ state, const int* __restrict__ idx,
    const char* __restrict__ ws)
{
  extern __shared__ char smem[];
  const int tid  = threadIdx.x;
  const int lane = tid & 63;
  const int w    = tid >> 6;
  const int b    = blockIdx.x;
  const int s0   = b * BT;
  int* idx_lds = (int*)(smem + L1_IDX);

  const unsigned short* w1img = (const unsigned short*)(ws + OFF_W1);
  const float* b1p = (const float*)(ws + OFF_B1);
  char* h1img = (char*)(ws) + OFF_H1;

  if (tid < BT) idx_lds[tid] = idx[s0 + tid];

  // state B-frags into regs (16x16x32: n = lane&15 sample, k = (lane>>4)*8+j)
  short8 bs[4];
  {
    const float* sp = state + (size_t)(s0 + w * 16 + (lane & 15)) * DIN + ((lane >> 4) << 3);
#pragma unroll
    for (int ks = 0; ks < 4; ++ks) {
      float v[8];
      f32x4 t0 = *(const f32x4*)(sp + ks * 32);
      f32x4 t1 = *(const f32x4*)(sp + ks * 32 + 4);
      v[0]=t0[0];v[1]=t0[1];v[2]=t0[2];v[3]=t0[3];
      v[4]=t1[0];v[5]=t1[1];v[6]=t1[2];v[7]=t1[3];
      bs[ks] = pack8(v);
    }
  }
  __syncthreads();

  const int g_lo = idx_lds[0];
  const int g_hi = idx_lds[BT - 1];
  const int myg  = idx_lds[w * 16 + (lane & 15)];
  const char* w1src = (const char*)w1img + (size_t)g_lo * NCHUNK * 8192;

  // prologue: stage chunks 0,1 (1 load/thread each)
  stage1k(L1_W1SLAB + 0 * 8192u + tid * 16, w1src + 0 * 8192 + tid * 16);
  stage1k(L1_W1SLAB + 1 * 8192u + tid * 16, w1src + 1 * 8192 + tid * 16);

  // store-address constants
  const int ntl  = w >> 1;
  const int s32  = (w & 1) * 16 + (lane & 15);
  const int k0   = (lane >> 4) << 2;      // 0,4,8,12
  const int half = k0 >> 3;
  const int j0h  = (k0 & 7) >> 2;         // 0 or 1 (8B half within slot)

  for (int c = 0; c < NCHUNK; ++c) {
    if (c < NCHUNK - 1) { asm volatile("s_waitcnt vmcnt(1)" ::: "memory"); }
    else                { asm volatile("s_waitcnt vmcnt(0)" ::: "memory"); }
    __builtin_amdgcn_sched_barrier(0);
    __builtin_amdgcn_s_barrier();
    if (c + 2 < NCHUNK)
      stage1k(L1_W1SLAB + (unsigned)((c + 2) * 8192) + tid * 16,
              w1src + (c + 2) * 8192 + tid * 16);

#pragma unroll
    for (int ft = 0; ft < 2; ++ft) {
      f32x4 kept; kept[0]=0.f; kept[1]=0.f; kept[2]=0.f; kept[3]=0.f;
      for (int g = g_lo; g <= g_hi; ++g) {
        f32x4 a1; a1[0]=0.f; a1[1]=0.f; a1[2]=0.f; a1[3]=0.f;
#pragma unroll
        for (int ks = 0; ks < 4; ++ks) {
          short8 aw;
          if (g == g_lo)
            aw = *(const short8*)(smem + L1_W1SLAB + (unsigned)(((c * 8 + ks * 2 + ft) * 64 + lane) * 16));
          else
            aw = *(const short8*)(w1img + (((size_t)(g * NCHUNK + c) * 8 + ks * 2 + ft) * 64 + lane) * 8);
          a1 = __builtin_amdgcn_mfma_f32_16x16x32_bf16(aw, bs[ks], a1, 0, 0, 0);
        }
        if (myg == g) kept = a1;
      }
      // bias + relu + pack 4 bf16 -> 8B store into h1 image
      const int f0 = (c * 2 + ft) * 16 + k0;
      unsigned long long pk = 0ull;
#pragma unroll
      for (int r = 0; r < 4; ++r) {
        float hv = fmaxf(kept[r] + b1p[myg * H1P + f0 + r], 0.f);
        pk |= ((unsigned long long)f2bf(hv)) << (16 * r);
      }
      const size_t unit = (((size_t)(b * NCHUNK + c) * 2 + ft) * 4 + ntl);
      ((unsigned long long*)(h1img + unit * 1024))[(half * 32 + s32) * 2 + j0h] = pk;
    }
  }
}

// ---------------- L2: GEMM over K=608 + W2a init + epilogue ----------------
// 256 blocks x 512 thr, 1/CU. Wave w: cols [w*64, w*64+64) (ct = 2w,2w+1),
// all 128 samples (nt 0..3). acc[2][4] f32x16 (128 AGPR).
__global__ __launch_bounds__(NTHR, 2) void l2_kernel(
    const float* __restrict__ action, const int* __restrict__ idx,
    const float* __restrict__ b3, const char* __restrict__ ws,
    float* __restrict__ out)
{
  extern __shared__ char smem[];
  const int tid  = threadIdx.x;
  const int lane = tid & 63;
  const int w    = tid >> 6;
  const int b    = blockIdx.x;
  const int s0   = b * BT;
  int* idx_lds = (int*)(smem + L2_IDX);

  const unsigned short* w2aimg = (const unsigned short*)(ws + OFF_W2A);
  const float* b2sp = (const float*)(ws + OFF_B2S);
  const float* w3p  = (const float*)(ws + OFF_W3);
  const char* w2ssrc = ws + OFF_W2S;
  const char* h1src  = ws + OFF_H1 + (size_t)b * NCHUNK * 8192;

  if (tid < BT) idx_lds[tid] = idx[s0 + tid];

  // action B-frags (all 4 nt tiles)
  short8 bact[4];
#pragma unroll
  for (int nt = 0; nt < 4; ++nt) {
    const float* ap = action + (size_t)(s0 + nt * 32 + (lane & 31)) * ACT + ((lane >> 5) << 3);
    float v[8];
    f32x4 a0 = *(const f32x4*)ap, a1 = *(const f32x4*)(ap + 4);
    v[0]=a0[0];v[1]=a0[1];v[2]=a0[2];v[3]=a0[3];
    v[4]=a1[0];v[5]=a1[1];v[6]=a1[2];v[7]=a1[3];
    bact[nt] = pack8(v);
  }
  __syncthreads();

  const int g_lo = idx_lds[0];
  const int g_hi = idx_lds[BT - 1];

  // acc init: h2a = W2a[g].action, per-sample masked
  f32x16 acc[2][4];
#pragma unroll
  for (int a = 0; a < 2; ++a)
#pragma unroll
    for (int n = 0; n < 4; ++n)
#pragma unroll
      for (int r = 0; r < 16; ++r) acc[a][n][r] = 0.f;
  for (int g = g_lo; g <= g_hi; ++g) {
#pragma unroll
    for (int cti = 0; cti < 2; ++cti) {
      const int ctg = w * 2 + cti;
      short8 af = *(const short8*)(w2aimg + (((size_t)g * 16 + ctg) * 64 + lane) * 8);
#pragma unroll
      for (int nt = 0; nt < 4; ++nt) {
        f32x16 z;
#pragma unroll
        for (int r = 0; r < 16; ++r) z[r] = 0.f;
        f32x16 t = __builtin_amdgcn_mfma_f32_32x32x16_bf16(af, bact[nt], z, 0, 0, 0);
        const bool p = (idx_lds[nt * 32 + (lane & 31)] == g);
#pragma unroll
        for (int r = 0; r < 16; ++r) acc[cti][nt][r] = p ? t[r] : acc[cti][nt][r];
      }
    }
  }

  // prologue stages: steps 0 -> buf0, 1 -> buf1 (5 loads/thread each)
#pragma unroll
  for (int u = 0; u < 4; ++u)
    stage1k(L2_W2S + (unsigned)(u * 8192) + tid * 16, w2ssrc + 0 * 32768 + u * 8192 + tid * 16);
  stage1k(L2_H1B + (unsigned)(tid * 16), h1src + 0 * 8192 + tid * 16);
#pragma unroll
  for (int u = 0; u < 4; ++u)
    stage1k(L2_W2S + (unsigned)(32768 + u * 8192) + tid * 16, w2ssrc + 1 * 32768 + u * 8192 + tid * 16);
  stage1k(L2_H1B + (unsigned)(8192 + tid * 16), h1src + 1 * 8192 + tid * 16);

  asm volatile("s_waitcnt vmcnt(5)" ::: "memory");
  __builtin_amdgcn_sched_barrier(0);
  __builtin_amdgcn_s_barrier();

  // K-loop: 19 steps of 32
  for (int i = 0; i < NCHUNK; ++i) {
    const int cur = i & 1;
    // ds-load frags for step i
    short8 af[2][2], bf[2][4];
#pragma unroll
    for (int t = 0; t < 2; ++t) {
#pragma unroll
      for (int cti = 0; cti < 2; ++cti)
        af[t][cti] = *(const short8*)(smem + L2_W2S + (unsigned)(cur * 32768 + ((t * 16 + w * 2 + cti) * 64 + lane) * 16));
#pragma unroll
      for (int nt = 0; nt < 4; ++nt)
        bf[t][nt] = *(const short8*)(smem + L2_H1B + (unsigned)(cur * 8192 + ((t * 4 + nt) * 64 + lane) * 16));
    }
    asm volatile("s_waitcnt lgkmcnt(0)" ::: "memory");
    __builtin_amdgcn_sched_barrier(0);
    __builtin_amdgcn_s_barrier();

    // stage step i+2 into buf cur (now safe: all waves done reading it)
    if (i + 2 < NCHUNK) {
#pragma unroll
      for (int u = 0; u < 4; ++u)
        stage1k(L2_W2S + (unsigned)(cur * 32768 + u * 8192) + tid * 16,
                w2ssrc + (size_t)(i + 2) * 32768 + u * 8192 + tid * 16);
      stage1k(L2_H1B + (unsigned)(cur * 8192) + tid * 16,
              h1src + (size_t)(i + 2) * 8192 + tid * 16);
    }

    __builtin_amdgcn_s_setprio(1);
#pragma unroll
    for (int t = 0; t < 2; ++t)
#pragma unroll
      for (int cti = 0; cti < 2; ++cti)
#pragma unroll
        for (int nt = 0; nt < 4; ++nt)
          acc[cti][nt] = __builtin_amdgcn_mfma_f32_32x32x16_bf16(af[t][cti], bf[t][nt], acc[cti][nt], 0, 0, 0);
    __builtin_amdgcn_s_setprio(0);

    if (i + 2 < NCHUNK) { asm volatile("s_waitcnt vmcnt(5)" ::: "memory"); }
    else                { asm volatile("s_waitcnt vmcnt(0)" ::: "memory"); }
    __builtin_amdgcn_sched_barrier(0);
    __builtin_amdgcn_s_barrier();
  }

  // epilogue: bias + relu + W3[g] dot, LDS reduce, plain store
  float qp[4] = {0.f, 0.f, 0.f, 0.f};
  int gs[4];
#pragma unroll
  for (int nt = 0; nt < 4; ++nt) gs[nt] = idx_lds[nt * 32 + (lane & 31)];
#pragma unroll
  for (int cti = 0; cti < 2; ++cti) {
    const int cbase = (w * 2 + cti) * 32 + ((lane >> 5) << 2);
#pragma unroll
    for (int r = 0; r < 16; ++r) {
      const int c = cbase + (r & 3) + ((r >> 2) << 3);
      const float b2v = b2sp[c];
#pragma unroll
      for (int nt = 0; nt < 4; ++nt) {
        float v2 = fmaxf(acc[cti][nt][r] + b2v, 0.f);
        qp[nt] += v2 * w3p[gs[nt] * H2P + c];
      }
    }
  }
  float* red = (float*)(smem + L2_RED);
#pragma unroll
  for (int nt = 0; nt < 4; ++nt) {
    float v = qp[nt] + __shfl_xor(qp[nt], 32, 64);
    if (lane < 32) red[w * 128 + nt * 32 + lane] = v;
  }
  __syncthreads();
  if (tid < BT) {
    float s = 0.f;
#pragma unroll
    for (int ww = 0; ww < 8; ++ww) s += red[ww * 128 + tid];
    out[s0 + tid] = s + b3[idx_lds[tid]];
  }
}

extern "C" void kernel_launch(void* const* d_in, const int* in_sizes, int n_in,
                              void* d_out, int out_size, void* d_ws, size_t ws_size,
                              hipStream_t stream) {
  const float* state  = (const float*)d_in[0];
  const float* action = (const float*)d_in[1];
  const int*   idx    = (const int*)d_in[2];
  const float* W1     = (const float*)d_in[3];
  const float* b1     = (const float*)d_in[4];
  const float* W2s    = (const float*)d_in[5];
  const float* b2s    = (const float*)d_in[6];
  const float* W2a    = (const float*)d_in[7];
  const float* W3     = (const float*)d_in[8];
  const float* b3     = (const float*)d_in[9];
  float* out = (float*)d_out;
  char* ws = (char*)d_ws;

  (void)hipFuncSetAttribute((const void*)l1_kernel,
                            hipFuncAttributeMaxDynamicSharedMemorySize, L1_TOTAL);
  (void)hipFuncSetAttribute((const void*)l2_kernel,
                            hipFuncAttributeMaxDynamicSharedMemorySize, L2_TOTAL);

  hipLaunchKernelGGL(prep_kernel, dim3(512), dim3(256), 0, stream,
                     W1, b1, W2s, b2s, W2a, W3, ws);
  hipLaunchKernelGGL(l1_kernel, dim3(NBLK), dim3(NTHR), L1_TOTAL, stream,
                     state, idx, ws);
  hipLaunchKernelGGL(l2_kernel, dim3(NBLK), dim3(NTHR), L2_TOTAL, stream,
                     action, idx, b3, ws, out);
}